// Round 4
// baseline (40.604 us; speedup 1.0000x reference)
//
#include <hip/hip_runtime.h>

// One-sided Chamfer: out[b][m] = min_n || point[b][m] - input[b][n] ||^2
// B=2, N=8192, M=8192, D=3, fp32.
//
// Stage 1: brute force, t = 0.5*|q|^2 - p.q (3 FMA/pair, min3 fused merge).
//   QPT=8 queries/thread amortizes each broadcast ds_read_b128 over 8
//   queries; BQ=256 & NSPLIT=128 keep 1024 blocks = 4/CU = 4 waves/SIMD
//   (round-3's 2 waves/SIMD regressed). Per-CU pipe load: VALU ~6 us,
//   LDS ~5.1 us -> VALU-bound with good overlap.
// Stage 2: min-reduce NSPLIT partials; one scalar output per thread,
//   coalesced per-y rows, ws is L2-resident.

constexpr int BB = 2;
constexpr int NN = 8192;
constexpr int MM = 8192;

constexpr int BQ = 256;            // threads per block (stage 1)
constexpr int QPT = 8;             // queries per thread
constexpr int QBLK = BQ * QPT;     // 2048 queries per block
constexpr int NSPLIT = 128;        // N slices -> 1024 blocks (4/CU)
constexpr int SLICE = NN / NSPLIT; // 64 refs per block (1 KB LDS as float4)
constexpr int BM = BB * MM;        // 16384 outputs

__global__ __launch_bounds__(BQ) void chamfer_partial_kernel(
    const float* __restrict__ input,   // [B, N, 3]
    const float* __restrict__ point,   // [B, M, 3]
    float* __restrict__ ws)            // [NSPLIT, B, M] partial minima
{
    __shared__ float4 ref[SLICE];

    const int b   = blockIdx.z;
    const int y   = blockIdx.y;
    const int n0  = y * SLICE;
    const int m0  = blockIdx.x * QBLK;
    const int tid = threadIdx.x;

    // --- stage reference slice into LDS with precomputed 0.5*|q|^2 ---
    if (tid < SLICE) {
        const float* inb = input + (size_t)b * NN * 3;
        const int n = n0 + tid;
        const float x = inb[n * 3 + 0];
        const float yy = inb[n * 3 + 1];
        const float z = inb[n * 3 + 2];
        ref[tid] = make_float4(x, yy, z, 0.5f * (x * x + yy * yy + z * z));
    }

    // --- load this thread's queries into registers (negated for FMA) ---
    const float* ptb = point + (size_t)b * MM * 3;
    float nx[QPT], ny[QPT], nz[QPT], p2[QPT], tmin[QPT];
#pragma unroll
    for (int q = 0; q < QPT; ++q) {
        const int m = m0 + q * BQ + tid;
        const float x = ptb[m * 3 + 0];
        const float yy = ptb[m * 3 + 1];
        const float z = ptb[m * 3 + 2];
        nx[q] = -x; ny[q] = -yy; nz[q] = -z;
        p2[q] = x * x + yy * yy + z * z;
        tmin[q] = 3.0e38f;
    }

    __syncthreads();

    // --- inner loop: 2 refs/iter, 8 queries each; min3-fused merge ---
#pragma unroll 4
    for (int j = 0; j < SLICE; j += 2) {
        const float4 r0 = ref[j];
        const float4 r1 = ref[j + 1];
#pragma unroll
        for (int q = 0; q < QPT; ++q) {
            float s0 = fmaf(nx[q], r0.x, r0.w);
            s0 = fmaf(ny[q], r0.y, s0);
            s0 = fmaf(nz[q], r0.z, s0);
            float s1 = fmaf(nx[q], r1.x, r1.w);
            s1 = fmaf(ny[q], r1.y, s1);
            s1 = fmaf(nz[q], r1.z, s1);
            tmin[q] = fminf(fminf(tmin[q], s0), s1);  // -> v_min3_f32
        }
    }

    // --- plain store of this slice's partial d2 (no init, no atomics) ---
    float* wsy = ws + (size_t)y * BM + (size_t)b * MM;
#pragma unroll
    for (int q = 0; q < QPT; ++q) {
        const int m = m0 + q * BQ + tid;
        wsy[m] = fmaxf(fmaf(2.0f, tmin[q], p2[q]), 0.0f);
    }
}

// out[o] = min over y of ws[y][o]; one scalar output per thread.
// 16384 threads = 64 blocks x 256; per-y rows are fully coalesced.
constexpr int RB = 256;
constexpr int RGRID = BM / RB;     // 64 blocks

__global__ __launch_bounds__(RB) void chamfer_reduce_kernel(
    const float* __restrict__ ws,  // [NSPLIT, BM]
    float* __restrict__ out)       // [BM]
{
    const int o = blockIdx.x * RB + threadIdx.x;
    float acc = ws[o];
#pragma unroll 8
    for (int y = 1; y < NSPLIT; ++y)
        acc = fminf(acc, ws[(size_t)y * BM + o]);
    out[o] = acc;
}

extern "C" void kernel_launch(void* const* d_in, const int* in_sizes, int n_in,
                              void* d_out, int out_size, void* d_ws, size_t ws_size,
                              hipStream_t stream) {
    const float* input = (const float*)d_in[0];  // [B, N, 3]
    const float* point = (const float*)d_in[1];  // [B, M, 3]
    float* out = (float*)d_out;                  // [B, M]
    float* ws  = (float*)d_ws;                   // [NSPLIT, B, M] = 8 MB

    dim3 grid1(MM / QBLK, NSPLIT, BB);
    chamfer_partial_kernel<<<grid1, dim3(BQ), 0, stream>>>(input, point, ws);

    chamfer_reduce_kernel<<<dim3(RGRID), dim3(RB), 0, stream>>>(ws, out);
}

// Round 5
// 26.575 us; speedup vs baseline: 1.5279x; 1.5279x over previous
//
#include <hip/hip_runtime.h>

// One-sided Chamfer: out[b][m] = min_n || point[b][m] - input[b][n] ||^2
// B=2, N=8192, M=8192, D=3, fp32.
//
// K0 (prep): repack input -> refs4[b*N+n] = (x, y, z, 0.5*|q|^2) in d_ws,
//            and init out[o] = +inf bits (0x7F800000).
// K1 (main): NO LDS. The ref stream is wave-uniform, so refs4 reads promote
//            to scalar s_load (SMEM pipe, otherwise idle) / L1-broadcast --
//            frees the LDS pipe that bounded rounds 1-2 (~10 us at QPT=4).
//            t = 0.5*|q|^2 - p.q (3 FMA/pair), per-slice min, then exact
//            atomicMin on the uint bit pattern (d2 >= 0 -> order-isomorphic).
// Proven shape from r2: BQ=256, QPT=4, NSPLIT=64 -> 1024 blocks, 4 waves/SIMD
// (QPT=8 regressed twice -> register pressure; stay at 4).

constexpr int BB = 2;
constexpr int NN = 8192;
constexpr int MM = 8192;

constexpr int BQ = 256;            // threads per block (main)
constexpr int QPT = 4;             // queries per thread
constexpr int QBLK = BQ * QPT;     // 1024 queries per block
constexpr int NSPLIT = 64;         // N slices -> 1024 blocks (4/CU)
constexpr int SLICE = NN / NSPLIT; // 128 refs per slice
constexpr int BM = BB * MM;        // 16384 outputs (== BB*NN too)

__global__ __launch_bounds__(256) void chamfer_prep_kernel(
    const float* __restrict__ input,   // [B, N, 3]
    float4* __restrict__ refs4,        // [B*N] packed refs in d_ws
    unsigned int* __restrict__ out)    // [B*M] init to +inf bits
{
    const int i = blockIdx.x * 256 + threadIdx.x;   // 0 .. BM-1 (BM == BB*NN)
    const float x = input[i * 3 + 0];
    const float y = input[i * 3 + 1];
    const float z = input[i * 3 + 2];
    refs4[i] = make_float4(x, y, z, 0.5f * (x * x + y * y + z * z));
    out[i] = 0x7F800000u;  // +inf (uint order == float order for d2 >= 0)
}

__global__ __launch_bounds__(BQ) void chamfer_main_kernel(
    const float4* __restrict__ refs4,  // [B*N]
    const float* __restrict__ point,   // [B, M, 3]
    unsigned int* __restrict__ out)    // [B*M], pre-init +inf
{
    const int b   = blockIdx.z;
    const int m0  = blockIdx.x * QBLK;
    const int tid = threadIdx.x;

    // --- this thread's queries in registers (negated for FMA) ---
    const float* ptb = point + (size_t)b * MM * 3;
    float nx[QPT], ny[QPT], nz[QPT], p2[QPT], tmin[QPT];
#pragma unroll
    for (int q = 0; q < QPT; ++q) {
        const int m = m0 + q * BQ + tid;
        const float x = ptb[m * 3 + 0];
        const float y = ptb[m * 3 + 1];
        const float z = ptb[m * 3 + 2];
        nx[q] = -x; ny[q] = -y; nz[q] = -z;
        p2[q] = x * x + y * y + z * z;
        tmin[q] = 3.0e38f;
    }

    // --- wave-uniform ref stream: scalar-promotable loads, no LDS ---
    const float4* rp = refs4 + (size_t)b * NN + (size_t)blockIdx.y * SLICE;
#pragma unroll 4
    for (int j = 0; j < SLICE; j += 2) {
        const float4 r0 = rp[j];
        const float4 r1 = rp[j + 1];
#pragma unroll
        for (int q = 0; q < QPT; ++q) {
            float s0 = fmaf(nx[q], r0.x, r0.w);
            s0 = fmaf(ny[q], r0.y, s0);
            s0 = fmaf(nz[q], r0.z, s0);
            float s1 = fmaf(nx[q], r1.x, r1.w);
            s1 = fmaf(ny[q], r1.y, s1);
            s1 = fmaf(nz[q], r1.z, s1);
            tmin[q] = fminf(fminf(tmin[q], s0), s1);  // -> v_min3_f32
        }
    }

    // --- exact merge across N-slices: atomicMin on uint bit pattern ---
    unsigned int* outb = out + (size_t)b * MM;
#pragma unroll
    for (int q = 0; q < QPT; ++q) {
        const int m = m0 + q * BQ + tid;
        const float d2 = fmaxf(fmaf(2.0f, tmin[q], p2[q]), 0.0f);
        atomicMin(outb + m, __float_as_uint(d2));
    }
}

extern "C" void kernel_launch(void* const* d_in, const int* in_sizes, int n_in,
                              void* d_out, int out_size, void* d_ws, size_t ws_size,
                              hipStream_t stream) {
    const float* input = (const float*)d_in[0];   // [B, N, 3]
    const float* point = (const float*)d_in[1];   // [B, M, 3]
    unsigned int* out  = (unsigned int*)d_out;    // [B, M] as uint bits
    float4* refs4      = (float4*)d_ws;           // 256 KB of scratch

    chamfer_prep_kernel<<<dim3(BM / 256), dim3(256), 0, stream>>>(input, refs4, out);

    dim3 grid(MM / QBLK, NSPLIT, BB);
    chamfer_main_kernel<<<grid, dim3(BQ), 0, stream>>>(refs4, point, out);
}